// Round 2
// baseline (4440.983 us; speedup 1.0000x reference)
//
#include <hip/hip_runtime.h>
#include <math.h>

// Problem constants (from reference): B=4, S=2048, HID=512, NH=8, DH=64
#define S_LEN 2048
#define HIDDIM 512
#define NHEAD 8
#define DHEAD 64
#define NBH 32      // B*NH
#define MTOT 8192   // B*S

// Fast HW transcendentals: v_exp_f32 computes 2^x, v_log_f32 computes log2(x).
// (glibc owns the __exp2f/__log2f names — use the amdgcn builtins directly.)
__device__ __forceinline__ float fast_exp2(float x) { return __builtin_amdgcn_exp2f(x); }
__device__ __forceinline__ float fast_log2(float x) { return __builtin_amdgcn_logf(x); }
// p = max(x,0)^pinv via exp2(log2(x)*pinv); log2(0)=-inf -> exp2(-inf)=0 handles clip.
__device__ __forceinline__ float powclip(float x, float pinv) {
    return fast_exp2(fast_log2(fmaxf(x, 0.f)) * pinv);
}

// ---------------------------------------------------------------------------
// Generic f32 GEMM: out = X @ W^T + bias, with output-layout modes.
//   X: [M,512] row-major, W: [N=512, K=512] row-major (torch Linear weight)
//   mode 0: out[m*512 + n]                     (plain)
//   mode 1: out[((b*NH+h)*S + s)*DH + d]       (QKV head layout)
//   mode 2: out[((b*NH+h)*DH + d)*S + s]       (K transposed: [bh][d][s])
// scale applied after bias (used to fold (alpha-1)/sqrt(DH) into Q).
// Tile: 64x64 per workgroup, 256 threads, 4x4 per thread, K-step 16.
// ---------------------------------------------------------------------------
__global__ __launch_bounds__(256) void gemm_xwt(
    const float* __restrict__ X, const float* __restrict__ W,
    const float* __restrict__ bias, float* __restrict__ out,
    int mode, float scale)
{
    __shared__ float Xs[16][68];   // [kk][m], pad 68 keeps float4 alignment + bank spread
    __shared__ float Ws[16][68];   // [kk][n]

    const int m0 = blockIdx.x * 64;
    const int n0 = blockIdx.y * 64;
    const int t  = threadIdx.x;
    const int tx = t & 15;         // n quad
    const int ty = t >> 4;         // m quad
    const int lrow = t >> 2;       // 0..63 staging row
    const int lk0  = (t & 3) << 2; // 0,4,8,12 staging k

    float acc[4][4];
#pragma unroll
    for (int i = 0; i < 4; ++i)
#pragma unroll
        for (int j = 0; j < 4; ++j) acc[i][j] = 0.f;

    for (int kt = 0; kt < HIDDIM; kt += 16) {
        float4 xv = *(const float4*)&X[(size_t)(m0 + lrow) * HIDDIM + kt + lk0];
        float4 wv = *(const float4*)&W[(size_t)(n0 + lrow) * HIDDIM + kt + lk0];
        __syncthreads();   // previous iteration's reads done
        Xs[lk0 + 0][lrow] = xv.x; Xs[lk0 + 1][lrow] = xv.y;
        Xs[lk0 + 2][lrow] = xv.z; Xs[lk0 + 3][lrow] = xv.w;
        Ws[lk0 + 0][lrow] = wv.x; Ws[lk0 + 1][lrow] = wv.y;
        Ws[lk0 + 2][lrow] = wv.z; Ws[lk0 + 3][lrow] = wv.w;
        __syncthreads();
#pragma unroll
        for (int kk = 0; kk < 16; ++kk) {
            float4 a = *(const float4*)&Xs[kk][ty << 2];
            float4 b = *(const float4*)&Ws[kk][tx << 2];
            float av[4] = {a.x, a.y, a.z, a.w};
            float bv[4] = {b.x, b.y, b.z, b.w};
#pragma unroll
            for (int i = 0; i < 4; ++i)
#pragma unroll
                for (int j = 0; j < 4; ++j) acc[i][j] += av[i] * bv[j];
        }
    }

#pragma unroll
    for (int i = 0; i < 4; ++i) {
        const int m  = m0 + (ty << 2) + i;
        const int bb = m >> 11;      // m / 2048
        const int ss = m & 2047;
#pragma unroll
        for (int j = 0; j < 4; ++j) {
            const int n = n0 + (tx << 2) + j;
            const float v = (acc[i][j] + bias[n]) * scale;
            size_t idx;
            if (mode == 0) {
                idx = (size_t)m * HIDDIM + n;
            } else {
                const int h = n >> 6, d = n & 63;
                if (mode == 1)
                    idx = ((size_t)(bb * NHEAD + h) * S_LEN + ss) * DHEAD + d;
                else
                    idx = ((size_t)(bb * NHEAD + h) * DHEAD + d) * S_LEN + ss;
            }
            out[idx] = v;
        }
    }
}

// ---------------------------------------------------------------------------
// Fused entmax-1.33 attention.
// Grid: 32 bh * 128 q-tiles = 4096 workgroups, 256 threads (4 waves).
// Each wave owns 4 query rows; each lane holds 32 k-slices of the score row
// in registers (sc[4][32]).  Q is pre-scaled by (alpha-1)/sqrt(DH) so sc = Xa.
// Bisection runs fully in registers with wave butterfly reductions.
// Final probs go to LDS for the PV pass.
// ---------------------------------------------------------------------------
__global__ __launch_bounds__(256) void attn_entmax(
    const float* __restrict__ Q,   // [32][2048][64], pre-scaled
    const float* __restrict__ Kt,  // [32][64][2048]
    const float* __restrict__ V,   // [32][2048][64]
    float* __restrict__ CTX,       // [8192][512]
    float pinv, float dm0)
{
    __shared__ float Qs[16][64];
    __shared__ float P[16][2052];  // pad 2052: float4-aligned, spreads banks by row
    __shared__ float rowsum[16];

    const int bh = blockIdx.x >> 7;
    const int q0 = (blockIdx.x & 127) << 4;
    const int t  = threadIdx.x;

    {   // load 16x64 Q tile
        const int r = t >> 4;
        const int d = (t & 15) << 2;
        *(float4*)&Qs[r][d] =
            *(const float4*)&Q[((size_t)bh * S_LEN + q0 + r) * DHEAD + d];
    }
    __syncthreads();

    const int w  = t >> 6;   // wave id: rows 4w..4w+3
    const int tc = t & 63;   // lane: k-slice owner

    float sc[4][32];
#pragma unroll
    for (int i = 0; i < 4; ++i)
#pragma unroll
        for (int j = 0; j < 32; ++j) sc[i][j] = 0.f;

    const float* KtB = Kt + (size_t)bh * DHEAD * S_LEN;

    // ---- Phase A: scores (Xa) into registers -----------------------------
#pragma unroll
    for (int kb = 0; kb < 8; ++kb) {
        const int kbase = (kb << 8) + (tc << 2);
        for (int dc = 0; dc < 16; ++dc) {
            const float* kp = KtB + (size_t)(dc << 2) * S_LEN + kbase;
            float4 k0 = *(const float4*)(kp);
            float4 k1 = *(const float4*)(kp + S_LEN);
            float4 k2 = *(const float4*)(kp + 2 * S_LEN);
            float4 k3 = *(const float4*)(kp + 3 * S_LEN);
#pragma unroll
            for (int i = 0; i < 4; ++i) {
                float4 q = *(const float4*)&Qs[(w << 2) + i][dc << 2];
                sc[i][(kb << 2) + 0] += q.x * k0.x + q.y * k1.x + q.z * k2.x + q.w * k3.x;
                sc[i][(kb << 2) + 1] += q.x * k0.y + q.y * k1.y + q.z * k2.y + q.w * k3.y;
                sc[i][(kb << 2) + 2] += q.x * k0.z + q.y * k1.z + q.z * k2.z + q.w * k3.z;
                sc[i][(kb << 2) + 3] += q.x * k0.w + q.y * k1.w + q.z * k2.w + q.w * k3.w;
            }
        }
    }

    // ---- Phase B: entmax bisection (in registers) ------------------------
    float tau[4], flo[4];
    float dm = dm0;
#pragma unroll
    for (int i = 0; i < 4; ++i) {
        float m = sc[i][0];
#pragma unroll
        for (int j = 1; j < 32; ++j) m = fmaxf(m, sc[i][j]);
#pragma unroll
        for (int o = 32; o > 0; o >>= 1) m = fmaxf(m, __shfl_xor(m, o, 64));
        tau[i] = m - 1.0f;
    }
    {   // f_lo (computed once, only its sign is used in updates)
        float ss[4] = {0.f, 0.f, 0.f, 0.f};
#pragma unroll
        for (int j = 0; j < 32; ++j)
#pragma unroll
            for (int i = 0; i < 4; ++i)
                ss[i] += powclip(sc[i][j] - tau[i], pinv);
#pragma unroll
        for (int i = 0; i < 4; ++i) {
#pragma unroll
            for (int o = 32; o > 0; o >>= 1) ss[i] += __shfl_xor(ss[i], o, 64);
            flo[i] = ss[i] - 1.0f;
        }
    }
    // 32 iterations == reference's 50 in f32 (dm < ulp(tau) afterwards)
    for (int it = 0; it < 32; ++it) {
        dm *= 0.5f;
        float tm[4], ss[4];
#pragma unroll
        for (int i = 0; i < 4; ++i) { tm[i] = tau[i] + dm; ss[i] = 0.f; }
#pragma unroll
        for (int j = 0; j < 32; ++j)
#pragma unroll
            for (int i = 0; i < 4; ++i)
                ss[i] += powclip(sc[i][j] - tm[i], pinv);
#pragma unroll
        for (int i = 0; i < 4; ++i) {
#pragma unroll
            for (int o = 32; o > 0; o >>= 1) ss[i] += __shfl_xor(ss[i], o, 64);
            if ((ss[i] - 1.0f) * flo[i] >= 0.f) tau[i] = tm[i];
        }
    }

    // ---- Phase C: final probs -> LDS, row sums ---------------------------
#pragma unroll
    for (int i = 0; i < 4; ++i) {
        float s = 0.f;
#pragma unroll
        for (int j = 0; j < 32; ++j) {
            float p = powclip(sc[i][j] - tau[i], pinv);
            sc[i][j] = p;
            s += p;
        }
#pragma unroll
        for (int o = 32; o > 0; o >>= 1) s += __shfl_xor(s, o, 64);
#pragma unroll
        for (int kb = 0; kb < 8; ++kb) {
            float4 pw = make_float4(sc[i][(kb << 2) + 0], sc[i][(kb << 2) + 1],
                                    sc[i][(kb << 2) + 2], sc[i][(kb << 2) + 3]);
            *(float4*)&P[(w << 2) + i][(kb << 8) + (tc << 2)] = pw;
        }
        if (tc == 0) rowsum[(w << 2) + i] = s;
    }
    __syncthreads();

    // ---- Phase D: PV ------------------------------------------------------
    const int r2 = t >> 4;          // 0..15 query row
    const int dq = (t & 15) << 2;   // d quad
    const float* VB = V + (size_t)bh * S_LEN * DHEAD;
    float ax = 0.f, ay = 0.f, az = 0.f, aw = 0.f;
    for (int k = 0; k < S_LEN; k += 4) {
        float4 p4 = *(const float4*)&P[r2][k];
        const float* vp = VB + (size_t)k * DHEAD + dq;
        float4 v0 = *(const float4*)(vp);
        float4 v1 = *(const float4*)(vp + DHEAD);
        float4 v2 = *(const float4*)(vp + 2 * DHEAD);
        float4 v3 = *(const float4*)(vp + 3 * DHEAD);
        ax += p4.x * v0.x + p4.y * v1.x + p4.z * v2.x + p4.w * v3.x;
        ay += p4.x * v0.y + p4.y * v1.y + p4.z * v2.y + p4.w * v3.y;
        az += p4.x * v0.z + p4.y * v1.z + p4.z * v2.z + p4.w * v3.z;
        aw += p4.x * v0.w + p4.y * v1.w + p4.z * v2.w + p4.w * v3.w;
    }
    const float rsc = 1.0f / rowsum[r2];
    const int b = bh >> 3, h = bh & 7;
    float4 o = make_float4(ax * rsc, ay * rsc, az * rsc, aw * rsc);
    *(float4*)&CTX[((size_t)b * S_LEN + q0 + r2) * HIDDIM + (h << 6) + dq] = o;
}

// ---------------------------------------------------------------------------
extern "C" void kernel_launch(void* const* d_in, const int* in_sizes, int n_in,
                              void* d_out, int out_size, void* d_ws, size_t ws_size,
                              hipStream_t stream)
{
    const float* hs = (const float*)d_in[0];
    const float* Wq = (const float*)d_in[1];
    const float* bq = (const float*)d_in[2];
    const float* Wk = (const float*)d_in[3];
    const float* bk = (const float*)d_in[4];
    const float* Wv = (const float*)d_in[5];
    const float* bv = (const float*)d_in[6];
    const float* Wo = (const float*)d_in[7];
    const float* bo = (const float*)d_in[8];
    float* out = (float*)d_out;

    // workspace: Q, Kt, V, CTX  (4 x 16.78 MB = 67.1 MB)
    const size_t per = (size_t)NBH * S_LEN * DHEAD;
    float* Qb  = (float*)d_ws;
    float* Ktb = Qb  + per;
    float* Vb  = Ktb + per;
    float* CTX = Vb  + per;

    const double am1d  = 1.33 - 1.0;                       // 0.33000000000000007
    const float qscale = (float)(am1d / 8.0);              // fold (a-1)/sqrt(DH) into Q
    const float pinv   = (float)(1.0 / am1d);              // 3.0303...
    // pow(1/2048, a-1) == 2^(-11*(a-1))
    const float dm0    = (float)(1.0 - exp2(-11.0 * am1d));

    dim3 gp(MTOT / 64, HIDDIM / 64);
    gemm_xwt<<<gp, 256, 0, stream>>>(hs, Wq, bq, Qb,  1, qscale);
    gemm_xwt<<<gp, 256, 0, stream>>>(hs, Wk, bk, Ktb, 2, 1.0f);
    gemm_xwt<<<gp, 256, 0, stream>>>(hs, Wv, bv, Vb,  1, 1.0f);
    attn_entmax<<<dim3(NBH * (S_LEN / 16)), 256, 0, stream>>>(Qb, Ktb, Vb, CTX, pinv, dm0);
    gemm_xwt<<<gp, 256, 0, stream>>>(CTX, Wo, bo, out, 0, 1.0f);
}